// Round 1
// baseline (230.209 us; speedup 1.0000x reference)
//
#include <hip/hip_runtime.h>

#define BATCH 8
#define SEQ 32768
#define DIM 128
#define QSCALE 0.08838834764831845f

typedef __attribute__((ext_vector_type(8))) short short8;
typedef __attribute__((ext_vector_type(8))) __bf16 bf16x8;
typedef __attribute__((ext_vector_type(16))) float f32x16;
typedef __attribute__((ext_vector_type(4))) float f32x4;

// row-major [R][128] bf16 tile, XOR swizzle to break 256B-stride bank conflicts
#define SWZ(r, c) ((((r) << 7) + (c)) ^ (((r) & 7) << 3))

__device__ __forceinline__ short bf16b(float f) {
  unsigned u = __builtin_bit_cast(unsigned, f);
  u += 0x7fffu + ((u >> 16) & 1u);   // round-to-nearest-even
  return (short)(u >> 16);
}

__device__ __forceinline__ f32x16 mfma16(const short* pa, const short* pb, f32x16 c) {
  bf16x8 a = *(const bf16x8*)pa;
  bf16x8 b = *(const bf16x8*)pb;
  return __builtin_amdgcn_mfma_f32_32x32x16_bf16(a, b, c, 0, 0, 0);
}

// ---------------------------------------------------------------------------
// Pass 1: q,k projection + softmax + ctx[b] = sum_n q^T k  (per-block partial)
// grid 256 = 8 batches x 32 strips of 1024 rows; 512 threads (8 waves)
// ---------------------------------------------------------------------------
__global__ __launch_bounds__(512, 1)
void la_pass1(const float* __restrict__ x, const float* __restrict__ Wqkv,
              float* __restrict__ partials) {
  __shared__ __align__(16) short Wt[256 * 128];   // Wt[col][j] = Wqkv[j][col], 64KB
  __shared__ __align__(16) short xs[32 * 128];    // 8KB
  __shared__ __align__(16) float P[32 * 256];     // 32KB
  __shared__ __align__(16) short qt[128 * 40];    // q^T [d][kk], pad 40, 10KB
  __shared__ __align__(16) short kt[128 * 40];    // 10KB

  const int tid = threadIdx.x;
  const int lane = tid & 63;
  const int wv = tid >> 6;
  const int b = blockIdx.x >> 5;
  const int strip = blockIdx.x & 31;
  const long n0 = (long)strip * 1024;

  for (int i = tid; i < 128 * 384; i += 512) {
    int j = i / 384;
    int c = i - j * 384;
    if (c < 256) Wt[SWZ(c, j)] = bf16b(Wqkv[i]);
  }

  f32x16 ctx0 = {0.0f};
  f32x16 ctx1 = {0.0f};
  const int td = wv & 3;            // d-tile of this wave
  const int teb = (wv >> 2) << 1;   // first e-tile of this wave
  const int l31 = lane & 31;
  const int koff = (lane >> 5) << 3;

  __syncthreads();

  for (int ch = 0; ch < 32; ++ch) {
    const long nb = (long)b * SEQ + n0 + ch * 32;
    const int li = tid << 3;
    const int lr = li >> 7;
    const int lc = li & 127;
    const float* xp = x + (nb + lr) * DIM + lc;
    f32x4 x0 = *(const f32x4*)xp;
    f32x4 x1 = *(const f32x4*)(xp + 4);

    __syncthreads();   // prev chunk fully consumed

    short8 xv;
    xv[0] = bf16b(x0[0]); xv[1] = bf16b(x0[1]); xv[2] = bf16b(x0[2]); xv[3] = bf16b(x0[3]);
    xv[4] = bf16b(x1[0]); xv[5] = bf16b(x1[1]); xv[6] = bf16b(x1[2]); xv[7] = bf16b(x1[3]);
    *(short8*)&xs[SWZ(lr, lc)] = xv;

    __syncthreads();

    // projection: P[32 x 256] ; wave wv covers cols [wv*32, wv*32+32)
    f32x16 accp = {0.0f};
    #pragma unroll
    for (int ks = 0; ks < 8; ++ks) {
      const int k0 = (ks << 4) + koff;
      accp = mfma16(&xs[SWZ(l31, k0)], &Wt[SWZ((wv << 5) + l31, k0)], accp);
    }
    #pragma unroll
    for (int r = 0; r < 16; ++r) {
      const int row = (r & 3) + ((r >> 2) << 3) + ((lane >> 5) << 2);
      P[(row << 8) + (wv << 5) + l31] = accp[r];
    }

    __syncthreads();

    // softmax: 64 tasks (32 rows x {q,k}), 8 threads each
    {
      const int task = tid >> 3;
      const int s = tid & 7;
      const int row = task & 31;
      const int half = task >> 5;
      const float* pr = &P[(row << 8) + (half << 7) + (s << 4)];
      float v[16];
      float mx = -3.0e38f;
      #pragma unroll
      for (int i = 0; i < 16; ++i) { v[i] = pr[i]; mx = fmaxf(mx, v[i]); }
      mx = fmaxf(mx, __shfl_xor(mx, 1));
      mx = fmaxf(mx, __shfl_xor(mx, 2));
      mx = fmaxf(mx, __shfl_xor(mx, 4));
      float sum = 0.0f;
      #pragma unroll
      for (int i = 0; i < 16; ++i) { v[i] = __expf(v[i] - mx); sum += v[i]; }
      sum += __shfl_xor(sum, 1);
      sum += __shfl_xor(sum, 2);
      sum += __shfl_xor(sum, 4);
      const float inv = (half ? 1.0f : QSCALE) / sum;
      short* dst = half ? kt : qt;
      #pragma unroll
      for (int i = 0; i < 16; ++i) {
        const int d = (s << 4) + i;
        dst[d * 40 + row] = bf16b(v[i] * inv);
      }
    }

    __syncthreads();

    // ctx += q^T k : K = 32 rows -> 2 ksteps; each wave owns 2 of 16 tiles
    #pragma unroll
    for (int ks = 0; ks < 2; ++ks) {
      const int kk = (ks << 4) + koff;
      const short* pa = &qt[((td << 5) + l31) * 40 + kk];
      ctx0 = mfma16(pa, &kt[((teb << 5) + l31) * 40 + kk], ctx0);
      ctx1 = mfma16(pa, &kt[(((teb + 1) << 5) + l31) * 40 + kk], ctx1);
    }
  }

  float* pout = partials + (long)blockIdx.x * 16384;
  #pragma unroll
  for (int r = 0; r < 16; ++r) {
    const int drow = (td << 5) + (r & 3) + ((r >> 2) << 3) + ((lane >> 5) << 2);
    pout[(drow << 7) + (teb << 5) + l31] = ctx0[r];
    pout[(drow << 7) + ((teb + 1) << 5) + l31] = ctx1[r];
  }
}

// ---------------------------------------------------------------------------
// Reduce 32 partials per batch -> ctx[b]  (grid 128 = 8 batches x 16 slices)
// ---------------------------------------------------------------------------
__global__ void la_reduce(const float* __restrict__ partials, float* __restrict__ ctx) {
  const int b = blockIdx.x >> 4;
  const int sl = blockIdx.x & 15;
  const int idx = (sl << 10) + ((int)threadIdx.x << 2);
  f32x4 acc = {0.0f};
  for (int st = 0; st < 32; ++st) {
    const f32x4 v = *(const f32x4*)(partials + ((long)((b << 5) + st) << 14) + idx);
    acc += v;
  }
  *(f32x4*)(ctx + ((long)b << 14) + idx) = acc;
}

// ---------------------------------------------------------------------------
// Mt[b][d'][e] = sum_d ctx[b][d][e] * Wout[d][d']   (bf16 out; grid 32)
// ---------------------------------------------------------------------------
__global__ void la_mkern(const float* __restrict__ ctx, const float* __restrict__ Wout,
                         short* __restrict__ Mtw) {
  __shared__ __align__(16) float cl[128 * 132];  // padded stride 132
  __shared__ float wo[128 * 32];
  const int tid = threadIdx.x;
  const int b = blockIdx.x >> 2;
  const int d0 = (blockIdx.x & 3) << 5;
  const float* cp = ctx + ((long)b << 14);
  for (int i = tid << 2; i < 16384; i += 1024) {
    f32x4 v = *(const f32x4*)(cp + i);
    *(f32x4*)&cl[(i >> 7) * 132 + (i & 127)] = v;
  }
  for (int i = tid; i < 128 * 32; i += 256) {
    wo[i] = Wout[((i >> 5) << 7) + d0 + (i & 31)];
  }
  __syncthreads();
  const int dq = tid >> 3;
  const int e0 = (tid & 7) << 4;
  float acc[16];
  #pragma unroll
  for (int i = 0; i < 16; ++i) acc[i] = 0.0f;
  for (int d = 0; d < 128; ++d) {
    const float w = wo[(d << 5) + dq];
    const float* c = &cl[d * 132 + e0];
    #pragma unroll
    for (int i = 0; i < 16; ++i) acc[i] += c[i] * w;
  }
  short* dst = Mtw + ((long)b << 14) + ((long)(d0 + dq) << 7) + e0;
  #pragma unroll
  for (int i = 0; i < 16; ++i) dst[i] = bf16b(acc[i]);
}

// ---------------------------------------------------------------------------
// Pass 2: v projection + softmax + out = v @ Mt^T(+bias)
// grid 256 = 8 batches x 32 strips of 1024 rows; 512 threads; 64-row chunks
// ---------------------------------------------------------------------------
__global__ __launch_bounds__(512, 1)
void la_pass2(const float* __restrict__ x, const float* __restrict__ Wqkv,
              const float* __restrict__ bout, const short* __restrict__ Mtw,
              float* __restrict__ out) {
  __shared__ __align__(16) short Wvt[128 * 128];  // 32KB
  __shared__ __align__(16) short Mt[128 * 128];   // 32KB
  __shared__ __align__(16) short xs[64 * 128];    // 16KB
  __shared__ __align__(16) float P[64 * 128];     // 32KB
  __shared__ __align__(16) short vs[64 * 128];    // 16KB

  const int tid = threadIdx.x;
  const int lane = tid & 63;
  const int wv = tid >> 6;
  const int b = blockIdx.x >> 5;
  const int strip = blockIdx.x & 31;
  const long n0 = (long)strip * 1024;
  const int rt = wv >> 2;
  const int ct = wv & 3;
  const int l31 = lane & 31;
  const int koff = (lane >> 5) << 3;

  for (int i = tid; i < 128 * 384; i += 512) {
    int j = i / 384;
    int c = i - j * 384;
    if (c >= 256) Wvt[SWZ(c - 256, j)] = bf16b(Wqkv[i]);
  }
  {
    const short* mp = Mtw + ((long)b << 14);
    for (int i = tid << 3; i < 16384; i += 4096) {
      *(short8*)&Mt[SWZ(i >> 7, i & 127)] = *(const short8*)(mp + i);
    }
  }
  const float bias = bout[(ct << 5) + l31];
  __syncthreads();

  for (int ch = 0; ch < 16; ++ch) {
    const long nb = (long)b * SEQ + n0 + ch * 64;
    const int li = tid << 4;
    const int lr = li >> 7;
    const int lc = li & 127;
    const float* xp = x + (nb + lr) * DIM + lc;
    f32x4 x0 = *(const f32x4*)xp;
    f32x4 x1 = *(const f32x4*)(xp + 4);
    f32x4 x2 = *(const f32x4*)(xp + 8);
    f32x4 x3 = *(const f32x4*)(xp + 12);

    __syncthreads();

    short8 xv0, xv1;
    #pragma unroll
    for (int i = 0; i < 4; ++i) {
      xv0[i] = bf16b(x0[i]); xv0[4 + i] = bf16b(x1[i]);
      xv1[i] = bf16b(x2[i]); xv1[4 + i] = bf16b(x3[i]);
    }
    *(short8*)&xs[SWZ(lr, lc)] = xv0;
    *(short8*)&xs[SWZ(lr, lc + 8)] = xv1;

    __syncthreads();

    // v projection: P[64 x 128]; wave (rt,ct) owns one 32x32 tile
    f32x16 accp = {0.0f};
    const int arow = (rt << 5) + l31;
    #pragma unroll
    for (int ks = 0; ks < 8; ++ks) {
      const int k0 = (ks << 4) + koff;
      accp = mfma16(&xs[SWZ(arow, k0)], &Wvt[SWZ((ct << 5) + l31, k0)], accp);
    }
    #pragma unroll
    for (int r = 0; r < 16; ++r) {
      const int row = (rt << 5) + (r & 3) + ((r >> 2) << 3) + ((lane >> 5) << 2);
      P[(row << 7) + (ct << 5) + l31] = accp[r];
    }

    __syncthreads();

    // softmax: 64 rows, 8 threads/row
    {
      const int row = tid >> 3;
      const int s = tid & 7;
      const float* pr = &P[(row << 7) + (s << 4)];
      float v[16];
      float mx = -3.0e38f;
      #pragma unroll
      for (int i = 0; i < 16; ++i) { v[i] = pr[i]; mx = fmaxf(mx, v[i]); }
      mx = fmaxf(mx, __shfl_xor(mx, 1));
      mx = fmaxf(mx, __shfl_xor(mx, 2));
      mx = fmaxf(mx, __shfl_xor(mx, 4));
      float sum = 0.0f;
      #pragma unroll
      for (int i = 0; i < 16; ++i) { v[i] = __expf(v[i] - mx); sum += v[i]; }
      sum += __shfl_xor(sum, 1);
      sum += __shfl_xor(sum, 2);
      sum += __shfl_xor(sum, 4);
      const float inv = 1.0f / sum;
      #pragma unroll
      for (int i = 0; i < 16; ++i) {
        vs[SWZ(row, (s << 4) + i)] = bf16b(v[i] * inv);
      }
    }

    __syncthreads();

    // out = v @ Mt(B)  : out[row][d'] = sum_e v[row][e] * Mt[d'][e]
    f32x16 acco = {0.0f};
    #pragma unroll
    for (int ks = 0; ks < 8; ++ks) {
      const int k0 = (ks << 4) + koff;
      acco = mfma16(&vs[SWZ(arow, k0)], &Mt[SWZ((ct << 5) + l31, k0)], acco);
    }
    float* op = out + (nb << 7) + (ct << 5) + l31;
    #pragma unroll
    for (int r = 0; r < 16; ++r) {
      const int row = (rt << 5) + (r & 3) + ((r >> 2) << 3) + ((lane >> 5) << 2);
      op[(long)row << 7] = acco[r] + bias;
    }
  }
}

extern "C" void kernel_launch(void* const* d_in, const int* in_sizes, int n_in,
                              void* d_out, int out_size, void* d_ws, size_t ws_size,
                              hipStream_t stream) {
  const float* x = (const float*)d_in[0];
  const float* Wqkv = (const float*)d_in[1];
  const float* Wout = (const float*)d_in[2];
  const float* bout = (const float*)d_in[3];
  float* out = (float*)d_out;
  float* partials = (float*)d_ws;                      // 256 * 16384 f32 = 16 MB
  float* ctx = partials + (size_t)256 * 16384;         // 8 * 16384 f32
  short* Mtw = (short*)(ctx + 8 * 16384);              // 8 * 16384 bf16
  la_pass1<<<dim3(256), dim3(512), 0, stream>>>(x, Wqkv, partials);
  la_reduce<<<dim3(128), dim3(256), 0, stream>>>(partials, ctx);
  la_mkern<<<dim3(32), dim3(256), 0, stream>>>(ctx, Wout, Mtw);
  la_pass2<<<dim3(256), dim3(512), 0, stream>>>(x, Wqkv, bout, Mtw, out);
}